// Round 7
// baseline (801.644 us; speedup 1.0000x reference)
//
#include <hip/hip_runtime.h>
#include <stdint.h>

#define BB 2
#define SS 2048
#define EE 1024
#define HH 16
#define DD 64
#define C1 0.18033688f  // 0.125 * log2(e): folded into Q at projection epilogue
#define NT (SS / 64)

typedef _Float16 h16;
typedef _Float16 f16x8 __attribute__((ext_vector_type(8)));
typedef _Float16 f16x4 __attribute__((ext_vector_type(4)));
typedef float f32x4 __attribute__((ext_vector_type(4)));

// XOR swizzle: 16B chunk j of row lives at slot (j ^ (row&7)) [rule #21: applied to the
// global SOURCE at stage time + to the LDS read addr; LDS dest stays linear]
#define SWZ(row, j) ((j) ^ ((row) & 7))

__device__ __forceinline__ void async_ld16(const void* g, void* l) {
  __builtin_amdgcn_global_load_lds((__attribute__((address_space(1))) void*)g,
                                   (__attribute__((address_space(3))) void*)l,
                                   16, 0, 0);
}

// ---------------- f32 -> f16 converts ----------------
__global__ __launch_bounds__(256) void cvt_qkv(const float* __restrict__ q,
                                               const float* __restrict__ k,
                                               const float* __restrict__ v,
                                               h16* __restrict__ oq, h16* __restrict__ ok,
                                               h16* __restrict__ ov, int n4) {
  const float* s;
  h16* d;
  if (blockIdx.y == 0) { s = q; d = oq; }
  else if (blockIdx.y == 1) { s = k; d = ok; }
  else { s = v; d = ov; }
  int i = blockIdx.x * 256 + threadIdx.x;
  if (i >= n4) return;
  const float4 t = reinterpret_cast<const float4*>(s)[i];
  f16x4 o = {(_Float16)t.x, (_Float16)t.y, (_Float16)t.z, (_Float16)t.w};
  *reinterpret_cast<f16x4*>(d + i * 4) = o;
}

__global__ __launch_bounds__(256) void cvt_w4(const float* __restrict__ w0, const float* __restrict__ w1,
                                              const float* __restrict__ w2, const float* __restrict__ w3,
                                              h16* __restrict__ o0, h16* __restrict__ o1,
                                              h16* __restrict__ o2, h16* __restrict__ o3, int n4) {
  const float* s;
  h16* d;
  if (blockIdx.y == 0) { s = w0; d = o0; }
  else if (blockIdx.y == 1) { s = w1; d = o1; }
  else if (blockIdx.y == 2) { s = w2; d = o2; }
  else { s = w3; d = o3; }
  int i = blockIdx.x * 256 + threadIdx.x;
  if (i >= n4) return;
  const float4 t = reinterpret_cast<const float4*>(s)[i];
  f16x4 o = {(_Float16)t.x, (_Float16)t.y, (_Float16)t.z, (_Float16)t.w};
  *reinterpret_cast<f16x4*>(d + i * 4) = o;
}

// ---------------- mask -> bit pack ----------------
__global__ __launch_bounds__(256) void pack_mask(const int* __restrict__ mask,
                                                 unsigned long long* __restrict__ pk) {
  const size_t i = (size_t)blockIdx.x * 256 + threadIdx.x;
  const unsigned long long b = __ballot(mask[i] != 0);
  if ((threadIdx.x & 63) == 0) pk[i >> 6] = b;
}

// ---------------- GEMM: C[4096,1024] = A * B^T + bias; tile 64x64, 4 waves ----------------
// MODE 0: [B,H,S,D] f16 (SCALEQ: *C1); MODE 1: [B,H,D,S] f16 (V^T); MODE 2: f32 [M,N].
template <int MODE, bool SCALEQ>
__global__ __launch_bounds__(256, 4) void gemm_bt(const h16* __restrict__ A,
                                                  const h16* __restrict__ Bw,
                                                  const float* __restrict__ bias,
                                                  void* __restrict__ out) {
  constexpr int K = EE;
  __shared__ h16 As[2][64 * 64];
  __shared__ h16 Bs[2][64 * 64];
  const int tid = threadIdx.x;
  const int lane = tid & 63, w = tid >> 6;
  const int cg = lane & 15, rg = lane >> 4;
  const int wr = w >> 1, wc = w & 1;
  const int row0 = blockIdx.y * 64, col0 = blockIdx.x * 64;

  f32x4 acc[2][2] = {};

  const h16* Ag = A + (size_t)row0 * K;
  const h16* Bg = Bw + (size_t)col0 * K;

  auto stage = [&](int k0, int bi) {
#pragma unroll
    for (int i = 0; i < 2; ++i) {
      const int c = i * 256 + tid, row = c >> 3, jg = SWZ(row, c & 7);
      async_ld16(Ag + (size_t)row * K + k0 + jg * 8, (char*)As[bi] + c * 16);
      async_ld16(Bg + (size_t)row * K + k0 + jg * 8, (char*)Bs[bi] + c * 16);
    }
  };

  stage(0, 0);
  __syncthreads();
  for (int ks = 0; ks < K / 64; ++ks) {
    const int cur = ks & 1;
    if (ks + 1 < K / 64) stage((ks + 1) * 64, cur ^ 1);
#pragma unroll
    for (int kk = 0; kk < 2; ++kk) {
      f16x8 af[2], bfr[2];
#pragma unroll
      for (int m = 0; m < 2; ++m) {
        const int row = wr * 32 + m * 16 + cg;
        af[m] = *(const f16x8*)&As[cur][row * 64 + SWZ(row, kk * 4 + rg) * 8];
      }
#pragma unroll
      for (int n = 0; n < 2; ++n) {
        const int row = wc * 32 + n * 16 + cg;
        bfr[n] = *(const f16x8*)&Bs[cur][row * 64 + SWZ(row, kk * 4 + rg) * 8];
      }
#pragma unroll
      for (int m = 0; m < 2; ++m)
#pragma unroll
        for (int n = 0; n < 2; ++n)
          acc[m][n] = __builtin_amdgcn_mfma_f32_16x16x32_f16(af[m], bfr[n], acc[m][n], 0, 0, 0);
    }
    __syncthreads();
  }

#pragma unroll
  for (int n = 0; n < 2; ++n) {
    const int col = col0 + wc * 32 + n * 16 + cg;
    const float bv = bias[col];
#pragma unroll
    for (int m = 0; m < 2; ++m) {
#pragma unroll
      for (int j = 0; j < 4; ++j) {
        const int row = row0 + wr * 32 + m * 16 + rg * 4 + j;
        float v = acc[m][n][j] + bv;
        if (SCALEQ) v *= C1;
        if (MODE == 2) {
          ((float*)out)[(size_t)row * EE + col] = v;
        } else {
          const int b = row >> 11, s = row & (SS - 1);
          const int h = col >> 6, d = col & (DD - 1);
          size_t idx;
          if (MODE == 0) idx = (((size_t)b * HH + h) * SS + s) * DD + d;   // [B,H,S,D]
          else           idx = (((size_t)b * HH + h) * DD + d) * SS + s;   // [B,H,D,S]
          ((h16*)out)[idx] = (_Float16)v;
        }
      }
    }
  }
}

// ---------------- flash attention fwd: 512 thr (8 waves), dbuf, swizzle, defer-max ----------------
// grid (S/128, B*H); wave owns 16 q-rows; KV tile 64. Q pre-scaled by C1.
// Writes O f16 [B,S,E] + C = m + log2(l) (exp2 domain; consistent with avg kernel).
__global__ __launch_bounds__(512, 4) void attn_fwd(
    const h16* __restrict__ Qh, const h16* __restrict__ Kh, const h16* __restrict__ Vt,
    const uint2* __restrict__ mpk, h16* __restrict__ O, float* __restrict__ Crow) {
  __shared__ h16 Ks[2][64 * 64];
  __shared__ h16 Vs[2][64 * 64];   // V^T tile: row = d
  __shared__ h16 Ps[8][16][72];    // per-wave P, stride 144B (16B-aligned)
  const int tid = threadIdx.x;
  const int lane = tid & 63, w = tid >> 6;
  const int cg = lane & 15, rg = lane >> 4;
  const int qt = blockIdx.x, bh = blockIdx.y;
  const int b = bh >> 4, h = bh & (HH - 1);
  const int q0 = qt * 128 + w * 16;

  const h16* Qbase = Qh + ((size_t)bh * SS + q0 + cg) * DD;
  const f16x8 qf0 = *(const f16x8*)(Qbase + rg * 8);
  const f16x8 qf1 = *(const f16x8*)(Qbase + 32 + rg * 8);

  f32x4 o[4] = {};
  float mrun[4] = {-INFINITY, -INFINITY, -INFINITY, -INFINITY};
  float lrun[4] = {0.f, 0.f, 0.f, 0.f};

  const h16* Kg = Kh + (size_t)bh * SS * DD;
  const h16* Vg = Vt + (size_t)bh * DD * SS;
  const uint2* mb = mpk + ((size_t)b * SS + q0) * NT;

  auto stage = [&](int k0, int bi) {  // 512 lanes: 1 chunk each for K and V
    const int row = tid >> 3, jg = SWZ(row, tid & 7);
    async_ld16(Kg + (size_t)(k0 + row) * DD + jg * 8, (char*)Ks[bi] + tid * 16);
    async_ld16(Vg + (size_t)row * SS + k0 + jg * 8, (char*)Vs[bi] + tid * 16);
  };

  stage(0, 0);
  __syncthreads();
  for (int kt = 0; kt < NT; ++kt) {
    const int cur = kt & 1;
    if (kt + 1 < NT) stage((kt + 1) * 64, cur ^ 1);

    uint2 pk[4];
#pragma unroll
    for (int j = 0; j < 4; ++j) pk[j] = mb[(rg * 4 + j) * NT + kt];

    // QK^T (Q pre-scaled: sc already in log2 domain)
    f32x4 sc[4];
#pragma unroll
    for (int n = 0; n < 4; ++n) {
      const int row = n * 16 + cg;
      const f16x8 kf0 = *(const f16x8*)&Ks[cur][row * 64 + SWZ(row, rg) * 8];
      const f16x8 kf1 = *(const f16x8*)&Ks[cur][row * 64 + SWZ(row, rg + 4) * 8];
      f32x4 z = {};
      z = __builtin_amdgcn_mfma_f32_16x16x32_f16(qf0, kf0, z, 0, 0, 0);
      sc[n] = __builtin_amdgcn_mfma_f32_16x16x32_f16(qf1, kf1, z, 0, 0, 0);
    }

    // unmasked row-max (safe: only shifts the shared exponent offset)
    float tmv[4];
#pragma unroll
    for (int j = 0; j < 4; ++j) {
      float a = fmaxf(fmaxf(sc[0][j], sc[1][j]), fmaxf(sc[2][j], sc[3][j]));
      a = fmaxf(a, __shfl_xor(a, 1));
      a = fmaxf(a, __shfl_xor(a, 2));
      a = fmaxf(a, __shfl_xor(a, 4));
      a = fmaxf(a, __shfl_xor(a, 8));
      tmv[j] = a;
    }
    // defer-max (T13, THR=8 in log2 domain): rescale only when some row grew >8
    const float need = fmaxf(fmaxf(tmv[0] - mrun[0], tmv[1] - mrun[1]),
                             fmaxf(tmv[2] - mrun[2], tmv[3] - mrun[3]));
    if (!__all(need <= 8.0f)) {
#pragma unroll
      for (int j = 0; j < 4; ++j) {
        const float mn = fmaxf(mrun[j], tmv[j]);
        const float scl = exp2f(mrun[j] - mn);
        mrun[j] = mn;
        lrun[j] *= scl;
#pragma unroll
        for (int n = 0; n < 4; ++n) o[n][j] *= scl;
      }
    }
    // P = exp2(sc - m) masked; row-sum into lrun
#pragma unroll
    for (int j = 0; j < 4; ++j) {
      float ps = 0.f;
#pragma unroll
      for (int n = 0; n < 4; ++n) {
        float p = exp2f(sc[n][j] - mrun[j]);
        const unsigned wb = (n & 2) ? pk[j].y : pk[j].x;
        p = ((wb >> ((n & 1) * 16 + cg)) & 1u) ? p : 0.f;
        ps += p;
        Ps[w][rg * 4 + j][n * 16 + cg] = (_Float16)p;
      }
      ps += __shfl_xor(ps, 1);
      ps += __shfl_xor(ps, 2);
      ps += __shfl_xor(ps, 4);
      ps += __shfl_xor(ps, 8);
      lrun[j] += ps;
    }

    // O += P * V (per-wave LDS round-trip; V from swizzled LDS)
#pragma unroll
    for (int kkb = 0; kkb < 2; ++kkb) {
      const f16x8 pa = *(const f16x8*)&Ps[w][cg][kkb * 32 + rg * 8];
#pragma unroll
      for (int n = 0; n < 4; ++n) {
        const int row = n * 16 + cg;
        const f16x8 vf = *(const f16x8*)&Vs[cur][row * 64 + SWZ(row, kkb * 4 + rg) * 8];
        o[n] = __builtin_amdgcn_mfma_f32_16x16x32_f16(pa, vf, o[n], 0, 0, 0);
      }
    }
    __syncthreads();
  }

  float rl[4];
#pragma unroll
  for (int j = 0; j < 4; ++j) rl[j] = 1.f / lrun[j];
#pragma unroll
  for (int n = 0; n < 4; ++n)
#pragma unroll
    for (int j = 0; j < 4; ++j) {
      const int s = q0 + rg * 4 + j;
      O[((size_t)b * SS + s) * EE + h * DD + n * 16 + cg] = (_Float16)(o[n][j] * rl[j]);
    }
  if (cg == 0) {
#pragma unroll
    for (int j = 0; j < 4; ++j) {
      const int s = q0 + rg * 4 + j;
      Crow[(size_t)bh * SS + s] = mrun[j] + __log2f(lrun[j]);
    }
  }
}

// ---------------- avg_attn: mean over heads, K staged via LDS dbuf (lean body) ----------------
// grid (kt, qt, b); 4 waves; wave owns 16 q-rows. Serial head loop; per head the 8KB
// K-tile is staged (stage h+1 before compute h, 1 barrier/iter). Q/C direct (L3-hot).
// Register-lean: bit-test mask (1 sgpr-ish reg), float4 C load. Q pre-scaled by C1.
__global__ __launch_bounds__(256, 4) void avg_attn_k(
    const h16* __restrict__ Qh, const h16* __restrict__ Kh,
    const uint2* __restrict__ mpk, const float* __restrict__ Crow,
    float* __restrict__ outAvg) {
  __shared__ h16 Ks[2][64 * 64];
  const int tid = threadIdx.x;
  const int lane = tid & 63, w = tid >> 6;
  const int cg = lane & 15, rg = lane >> 4;
  const int kt = blockIdx.x, qt = blockIdx.y, b = blockIdx.z;
  const int q0 = qt * 64 + w * 16, k0 = kt * 64;

  unsigned mbits = 0;  // 16 bits (j,n), reused across all heads
#pragma unroll
  for (int j = 0; j < 4; ++j) {
    const uint2 pk = mpk[((size_t)b * SS + q0 + rg * 4 + j) * NT + kt];
#pragma unroll
    for (int n = 0; n < 4; ++n) {
      const unsigned wbits = (n & 2) ? pk.y : pk.x;
      mbits |= ((wbits >> ((n & 1) * 16 + cg)) & 1u) << (j * 4 + n);
    }
  }

  auto stageK = [&](int hh, int bi) {
    const h16* Kg = Kh + (((size_t)(b * HH + hh) * SS) + k0) * DD;
#pragma unroll
    for (int i = 0; i < 2; ++i) {
      const int c = i * 256 + tid, row = c >> 3, jg = SWZ(row, c & 7);
      async_ld16(Kg + (size_t)row * DD + jg * 8, (char*)Ks[bi] + c * 16);
    }
  };

  const h16* Qq = Qh + (((size_t)b * HH) * SS + q0 + cg) * DD;  // head 0
  const float* Cq = Crow + ((size_t)b * HH) * SS + q0 + rg * 4;

  stageK(0, 0);
  __syncthreads();

  f32x4 acc[4] = {};
  for (int h = 0; h < HH; ++h) {
    const int cur = h & 1;
    if (h + 1 < HH) stageK(h + 1, cur ^ 1);
    const h16* Qb = Qq + (size_t)h * SS * DD;
    const f16x8 qf0 = *(const f16x8*)(Qb + rg * 8);
    const f16x8 qf1 = *(const f16x8*)(Qb + 32 + rg * 8);
    const float4 Cm = *(const float4*)(Cq + (size_t)h * SS);
#pragma unroll
    for (int n = 0; n < 4; ++n) {
      const int row = n * 16 + cg;
      const f16x8 kf0 = *(const f16x8*)&Ks[cur][row * 64 + SWZ(row, rg) * 8];
      const f16x8 kf1 = *(const f16x8*)&Ks[cur][row * 64 + SWZ(row, rg + 4) * 8];
      f32x4 z = {};
      z = __builtin_amdgcn_mfma_f32_16x16x32_f16(qf0, kf0, z, 0, 0, 0);
      const f32x4 sc = __builtin_amdgcn_mfma_f32_16x16x32_f16(qf1, kf1, z, 0, 0, 0);
      const float4 cmv = Cm;
#pragma unroll
      for (int j = 0; j < 4; ++j) {
        const float cj = (j == 0) ? cmv.x : (j == 1) ? cmv.y : (j == 2) ? cmv.z : cmv.w;
        const float p = exp2f(sc[j] - cj);
        acc[n][j] += ((mbits >> (j * 4 + n)) & 1u) ? p : 0.f;
      }
    }
    __syncthreads();
  }
#pragma unroll
  for (int n = 0; n < 4; ++n)
#pragma unroll
    for (int j = 0; j < 4; ++j)
      outAvg[((size_t)b * SS + q0 + rg * 4 + j) * SS + k0 + n * 16 + cg] = acc[n][j] * 0.0625f;
}

// ---------------- launch ----------------
extern "C" void kernel_launch(void* const* d_in, const int* in_sizes, int n_in,
                              void* d_out, int out_size, void* d_ws, size_t ws_size,
                              hipStream_t stream) {
  const float* query = (const float*)d_in[0];
  const float* key_  = (const float*)d_in[1];
  const float* value = (const float*)d_in[2];
  const int*   mask  = (const int*)d_in[3];
  const float* Wq = (const float*)d_in[4];
  const float* bq = (const float*)d_in[5];
  const float* Wk = (const float*)d_in[6];
  const float* bk = (const float*)d_in[7];
  const float* Wv = (const float*)d_in[8];
  const float* bv = (const float*)d_in[9];
  const float* Wo = (const float*)d_in[10];
  const float* bo = (const float*)d_in[11];

  const size_t SZ_SE = (size_t)BB * SS * EE;  // 4,194,304
  h16* qx  = (h16*)d_ws;
  h16* kx  = qx + SZ_SE;
  h16* vx  = kx + SZ_SE;
  h16* wqx = vx + SZ_SE;
  h16* wkx = wqx + EE * EE;
  h16* wvx = wkx + EE * EE;
  h16* wox = wvx + EE * EE;
  h16* Qd  = wox + EE * EE;     // [B,H,S,D], pre-scaled by C1
  h16* Kd  = Qd + SZ_SE;        // [B,H,S,D]
  h16* Vtd = Kd + SZ_SE;        // [B,H,D,S]
  h16* Od  = Vtd + SZ_SE;       // [B,S,E]
  float* Cr = (float*)(Od + SZ_SE);                 // B*H*S floats
  unsigned long long* mpk = (unsigned long long*)(Cr + (size_t)BB * HH * SS);  // 1 MB

  float* outp = (float*)d_out;
  float* avgp = outp + SZ_SE;

  pack_mask<<<(BB * SS * SS) / 256, 256, 0, stream>>>(mask, mpk);
  cvt_qkv<<<dim3(4096, 3), 256, 0, stream>>>(query, key_, value, qx, kx, vx, (int)(SZ_SE / 4));
  cvt_w4<<<dim3(1024, 4), 256, 0, stream>>>(Wq, Wk, Wv, Wo, wqx, wkx, wvx, wox, EE * EE / 4);

  gemm_bt<0, true ><<<dim3(16, 64), 256, 0, stream>>>(qx, wqx, bq, Qd);
  gemm_bt<0, false><<<dim3(16, 64), 256, 0, stream>>>(kx, wkx, bk, Kd);
  gemm_bt<1, false><<<dim3(16, 64), 256, 0, stream>>>(vx, wvx, bv, Vtd);

  attn_fwd<<<dim3(SS / 128, BB * HH), 512, 0, stream>>>(Qd, Kd, Vtd, (const uint2*)mpk, Od, Cr);

  avg_attn_k<<<dim3(SS / 64, SS / 64, BB), 256, 0, stream>>>(Qd, Kd, (const uint2*)mpk, Cr, avgp);

  gemm_bt<2, false><<<dim3(16, 64), 256, 0, stream>>>(Od, wox, bo, outp);
}

// Round 8
// 495.121 us; speedup vs baseline: 1.6191x; 1.6191x over previous
//
#include <hip/hip_runtime.h>
#include <stdint.h>

#define BB 2
#define SS 2048
#define EE 1024
#define HH 16
#define DD 64
#define C1 0.18033688f  // 0.125 * log2(e): folded into Q at projection epilogue
#define NT (SS / 64)

typedef _Float16 h16;
typedef _Float16 f16x8 __attribute__((ext_vector_type(8)));
typedef _Float16 f16x4 __attribute__((ext_vector_type(4)));
typedef float f32x4 __attribute__((ext_vector_type(4)));

// XOR swizzle: 16B chunk j of row lives at slot (j ^ (row&7)) [rule #21: applied to the
// global SOURCE at stage time + to the LDS read addr; LDS dest stays linear]
#define SWZ(row, j) ((j) ^ ((row) & 7))

__device__ __forceinline__ void async_ld16(const void* g, void* l) {
  __builtin_amdgcn_global_load_lds((__attribute__((address_space(1))) void*)g,
                                   (__attribute__((address_space(3))) void*)l,
                                   16, 0, 0);
}

// ---------------- f32 -> f16 converts ----------------
__global__ __launch_bounds__(256) void cvt_qkv(const float* __restrict__ q,
                                               const float* __restrict__ k,
                                               const float* __restrict__ v,
                                               h16* __restrict__ oq, h16* __restrict__ ok,
                                               h16* __restrict__ ov, int n4) {
  const float* s;
  h16* d;
  if (blockIdx.y == 0) { s = q; d = oq; }
  else if (blockIdx.y == 1) { s = k; d = ok; }
  else { s = v; d = ov; }
  int i = blockIdx.x * 256 + threadIdx.x;
  if (i >= n4) return;
  const float4 t = reinterpret_cast<const float4*>(s)[i];
  f16x4 o = {(_Float16)t.x, (_Float16)t.y, (_Float16)t.z, (_Float16)t.w};
  *reinterpret_cast<f16x4*>(d + i * 4) = o;
}

__global__ __launch_bounds__(256) void cvt_w4(const float* __restrict__ w0, const float* __restrict__ w1,
                                              const float* __restrict__ w2, const float* __restrict__ w3,
                                              h16* __restrict__ o0, h16* __restrict__ o1,
                                              h16* __restrict__ o2, h16* __restrict__ o3, int n4) {
  const float* s;
  h16* d;
  if (blockIdx.y == 0) { s = w0; d = o0; }
  else if (blockIdx.y == 1) { s = w1; d = o1; }
  else if (blockIdx.y == 2) { s = w2; d = o2; }
  else { s = w3; d = o3; }
  int i = blockIdx.x * 256 + threadIdx.x;
  if (i >= n4) return;
  const float4 t = reinterpret_cast<const float4*>(s)[i];
  f16x4 o = {(_Float16)t.x, (_Float16)t.y, (_Float16)t.z, (_Float16)t.w};
  *reinterpret_cast<f16x4*>(d + i * 4) = o;
}

// ---------------- mask -> bit pack ----------------
__global__ __launch_bounds__(256) void pack_mask(const int* __restrict__ mask,
                                                 unsigned long long* __restrict__ pk) {
  const size_t i = (size_t)blockIdx.x * 256 + threadIdx.x;
  const unsigned long long b = __ballot(mask[i] != 0);
  if ((threadIdx.x & 63) == 0) pk[i >> 6] = b;
}

// ---------------- GEMM: C[4096,1024] = A * B^T + bias; tile 64x64, 4 waves ----------------
// MODE 0: [B,H,S,D] f16 (SCALEQ: *C1); MODE 1: [B,H,D,S] f16 (V^T); MODE 2: f32 [M,N].
template <int MODE, bool SCALEQ>
__global__ __launch_bounds__(256, 4) void gemm_bt(const h16* __restrict__ A,
                                                  const h16* __restrict__ Bw,
                                                  const float* __restrict__ bias,
                                                  void* __restrict__ out) {
  constexpr int K = EE;
  __shared__ h16 As[2][64 * 64];
  __shared__ h16 Bs[2][64 * 64];
  const int tid = threadIdx.x;
  const int lane = tid & 63, w = tid >> 6;
  const int cg = lane & 15, rg = lane >> 4;
  const int wr = w >> 1, wc = w & 1;
  const int row0 = blockIdx.y * 64, col0 = blockIdx.x * 64;

  f32x4 acc[2][2] = {};

  const h16* Ag = A + (size_t)row0 * K;
  const h16* Bg = Bw + (size_t)col0 * K;

  auto stage = [&](int k0, int bi) {
#pragma unroll
    for (int i = 0; i < 2; ++i) {
      const int c = i * 256 + tid, row = c >> 3, jg = SWZ(row, c & 7);
      async_ld16(Ag + (size_t)row * K + k0 + jg * 8, (char*)As[bi] + c * 16);
      async_ld16(Bg + (size_t)row * K + k0 + jg * 8, (char*)Bs[bi] + c * 16);
    }
  };

  stage(0, 0);
  __syncthreads();
  for (int ks = 0; ks < K / 64; ++ks) {
    const int cur = ks & 1;
    if (ks + 1 < K / 64) stage((ks + 1) * 64, cur ^ 1);
#pragma unroll
    for (int kk = 0; kk < 2; ++kk) {
      f16x8 af[2], bfr[2];
#pragma unroll
      for (int m = 0; m < 2; ++m) {
        const int row = wr * 32 + m * 16 + cg;
        af[m] = *(const f16x8*)&As[cur][row * 64 + SWZ(row, kk * 4 + rg) * 8];
      }
#pragma unroll
      for (int n = 0; n < 2; ++n) {
        const int row = wc * 32 + n * 16 + cg;
        bfr[n] = *(const f16x8*)&Bs[cur][row * 64 + SWZ(row, kk * 4 + rg) * 8];
      }
#pragma unroll
      for (int m = 0; m < 2; ++m)
#pragma unroll
        for (int n = 0; n < 2; ++n)
          acc[m][n] = __builtin_amdgcn_mfma_f32_16x16x32_f16(af[m], bfr[n], acc[m][n], 0, 0, 0);
    }
    __syncthreads();
  }

#pragma unroll
  for (int n = 0; n < 2; ++n) {
    const int col = col0 + wc * 32 + n * 16 + cg;
    const float bv = bias[col];
#pragma unroll
    for (int m = 0; m < 2; ++m) {
#pragma unroll
      for (int j = 0; j < 4; ++j) {
        const int row = row0 + wr * 32 + m * 16 + rg * 4 + j;
        float v = acc[m][n][j] + bv;
        if (SCALEQ) v *= C1;
        if (MODE == 2) {
          ((float*)out)[(size_t)row * EE + col] = v;
        } else {
          const int b = row >> 11, s = row & (SS - 1);
          const int h = col >> 6, d = col & (DD - 1);
          size_t idx;
          if (MODE == 0) idx = (((size_t)b * HH + h) * SS + s) * DD + d;   // [B,H,S,D]
          else           idx = (((size_t)b * HH + h) * DD + d) * SS + s;   // [B,H,D,S]
          ((h16*)out)[idx] = (_Float16)v;
        }
      }
    }
  }
}

// ---------------- flash attention fwd: 512 thr (8 waves), dbuf, swizzle, defer-max ----------------
// grid (S/128, B*H); wave owns 16 q-rows; KV tile 64. Q pre-scaled by C1.
// Writes O f16 [B,S,E] + C = m + log2(l) (exp2 domain; consistent with avg kernel).
__global__ __launch_bounds__(512, 4) void attn_fwd(
    const h16* __restrict__ Qh, const h16* __restrict__ Kh, const h16* __restrict__ Vt,
    const uint2* __restrict__ mpk, h16* __restrict__ O, float* __restrict__ Crow) {
  __shared__ h16 Ks[2][64 * 64];
  __shared__ h16 Vs[2][64 * 64];   // V^T tile: row = d
  __shared__ h16 Ps[8][16][72];    // per-wave P, stride 144B (16B-aligned)
  const int tid = threadIdx.x;
  const int lane = tid & 63, w = tid >> 6;
  const int cg = lane & 15, rg = lane >> 4;
  const int qt = blockIdx.x, bh = blockIdx.y;
  const int b = bh >> 4, h = bh & (HH - 1);
  const int q0 = qt * 128 + w * 16;

  const h16* Qbase = Qh + ((size_t)bh * SS + q0 + cg) * DD;
  const f16x8 qf0 = *(const f16x8*)(Qbase + rg * 8);
  const f16x8 qf1 = *(const f16x8*)(Qbase + 32 + rg * 8);

  f32x4 o[4] = {};
  float mrun[4] = {-INFINITY, -INFINITY, -INFINITY, -INFINITY};
  float lrun[4] = {0.f, 0.f, 0.f, 0.f};

  const h16* Kg = Kh + (size_t)bh * SS * DD;
  const h16* Vg = Vt + (size_t)bh * DD * SS;
  const uint2* mb = mpk + ((size_t)b * SS + q0) * NT;

  auto stage = [&](int k0, int bi) {  // 512 lanes: 1 chunk each for K and V
    const int row = tid >> 3, jg = SWZ(row, tid & 7);
    async_ld16(Kg + (size_t)(k0 + row) * DD + jg * 8, (char*)Ks[bi] + tid * 16);
    async_ld16(Vg + (size_t)row * SS + k0 + jg * 8, (char*)Vs[bi] + tid * 16);
  };

  stage(0, 0);
  __syncthreads();
  for (int kt = 0; kt < NT; ++kt) {
    const int cur = kt & 1;
    if (kt + 1 < NT) stage((kt + 1) * 64, cur ^ 1);

    uint2 pk[4];
#pragma unroll
    for (int j = 0; j < 4; ++j) pk[j] = mb[(rg * 4 + j) * NT + kt];

    // QK^T (Q pre-scaled: sc already in log2 domain)
    f32x4 sc[4];
#pragma unroll
    for (int n = 0; n < 4; ++n) {
      const int row = n * 16 + cg;
      const f16x8 kf0 = *(const f16x8*)&Ks[cur][row * 64 + SWZ(row, rg) * 8];
      const f16x8 kf1 = *(const f16x8*)&Ks[cur][row * 64 + SWZ(row, rg + 4) * 8];
      f32x4 z = {};
      z = __builtin_amdgcn_mfma_f32_16x16x32_f16(qf0, kf0, z, 0, 0, 0);
      sc[n] = __builtin_amdgcn_mfma_f32_16x16x32_f16(qf1, kf1, z, 0, 0, 0);
    }

    // unmasked row-max (safe: only shifts the shared exponent offset)
    float tmv[4];
#pragma unroll
    for (int j = 0; j < 4; ++j) {
      float a = fmaxf(fmaxf(sc[0][j], sc[1][j]), fmaxf(sc[2][j], sc[3][j]));
      a = fmaxf(a, __shfl_xor(a, 1));
      a = fmaxf(a, __shfl_xor(a, 2));
      a = fmaxf(a, __shfl_xor(a, 4));
      a = fmaxf(a, __shfl_xor(a, 8));
      tmv[j] = a;
    }
    // defer-max (T13, THR=8 in log2 domain): rescale only when some row grew >8
    const float need = fmaxf(fmaxf(tmv[0] - mrun[0], tmv[1] - mrun[1]),
                             fmaxf(tmv[2] - mrun[2], tmv[3] - mrun[3]));
    if (!__all(need <= 8.0f)) {
#pragma unroll
      for (int j = 0; j < 4; ++j) {
        const float mn = fmaxf(mrun[j], tmv[j]);
        const float scl = exp2f(mrun[j] - mn);
        mrun[j] = mn;
        lrun[j] *= scl;
#pragma unroll
        for (int n = 0; n < 4; ++n) o[n][j] *= scl;
      }
    }
    // P = exp2(sc - m) masked; row-sum into lrun
#pragma unroll
    for (int j = 0; j < 4; ++j) {
      float ps = 0.f;
#pragma unroll
      for (int n = 0; n < 4; ++n) {
        float p = exp2f(sc[n][j] - mrun[j]);
        const unsigned wb = (n & 2) ? pk[j].y : pk[j].x;
        p = ((wb >> ((n & 1) * 16 + cg)) & 1u) ? p : 0.f;
        ps += p;
        Ps[w][rg * 4 + j][n * 16 + cg] = (_Float16)p;
      }
      ps += __shfl_xor(ps, 1);
      ps += __shfl_xor(ps, 2);
      ps += __shfl_xor(ps, 4);
      ps += __shfl_xor(ps, 8);
      lrun[j] += ps;
    }

    // O += P * V (per-wave LDS round-trip; V from swizzled LDS)
#pragma unroll
    for (int kkb = 0; kkb < 2; ++kkb) {
      const f16x8 pa = *(const f16x8*)&Ps[w][cg][kkb * 32 + rg * 8];
#pragma unroll
      for (int n = 0; n < 4; ++n) {
        const int row = n * 16 + cg;
        const f16x8 vf = *(const f16x8*)&Vs[cur][row * 64 + SWZ(row, kkb * 4 + rg) * 8];
        o[n] = __builtin_amdgcn_mfma_f32_16x16x32_f16(pa, vf, o[n], 0, 0, 0);
      }
    }
    __syncthreads();
  }

  float rl[4];
#pragma unroll
  for (int j = 0; j < 4; ++j) rl[j] = 1.f / lrun[j];
#pragma unroll
  for (int n = 0; n < 4; ++n)
#pragma unroll
    for (int j = 0; j < 4; ++j) {
      const int s = q0 + rg * 4 + j;
      O[((size_t)b * SS + s) * EE + h * DD + n * 16 + cg] = (_Float16)(o[n][j] * rl[j]);
    }
  if (cg == 0) {
#pragma unroll
    for (int j = 0; j < 4; ++j) {
      const int s = q0 + rg * 4 + j;
      Crow[(size_t)bh * SS + s] = mrun[j] + __log2f(lrun[j]);
    }
  }
}

// ---------------- avg_attn: mean over heads via score recompute (R2-exact structure) ----------------
// grid (kt, qt, b); 4 waves; wave owns 16 q-rows. Serial head loop, DIRECT global K/Q
// loads (L2/L3-resident; no LDS, no barriers — every staged/batched variant spilled:
// R4/R5/R6/R7). Q pre-scaled by C1; p = exp2(sc - C) with C = m + log2(l).
__global__ __launch_bounds__(256, 4) void avg_attn_k(
    const h16* __restrict__ Qh, const h16* __restrict__ Kh,
    const uint2* __restrict__ mpk, const float* __restrict__ Crow,
    float* __restrict__ outAvg) {
  const int tid = threadIdx.x;
  const int lane = tid & 63, w = tid >> 6;
  const int cg = lane & 15, rg = lane >> 4;
  const int kt = blockIdx.x, qt = blockIdx.y, b = blockIdx.z;
  const int q0 = qt * 64 + w * 16, k0 = kt * 64;

  unsigned mbits = 0;  // 16 bits (j,n), reused across all heads
#pragma unroll
  for (int j = 0; j < 4; ++j) {
    const uint2 pk = mpk[((size_t)b * SS + q0 + rg * 4 + j) * NT + kt];
#pragma unroll
    for (int n = 0; n < 4; ++n) {
      const unsigned wbits = (n & 2) ? pk.y : pk.x;
      mbits |= ((wbits >> ((n & 1) * 16 + cg)) & 1u) << (j * 4 + n);
    }
  }

  f32x4 acc[4] = {};
#pragma unroll 2
  for (int h = 0; h < HH; ++h) {
    const int bh = b * HH + h;
    const h16* Qb = Qh + ((size_t)bh * SS + q0 + cg) * DD;
    const f16x8 qf0 = *(const f16x8*)(Qb + rg * 8);
    const f16x8 qf1 = *(const f16x8*)(Qb + 32 + rg * 8);
    const h16* Kb = Kh + ((size_t)bh * SS + k0) * DD;
    const float4 Cm = *(const float4*)(Crow + (size_t)bh * SS + q0 + rg * 4);
#pragma unroll
    for (int n = 0; n < 4; ++n) {
      const h16* kr = Kb + (size_t)(n * 16 + cg) * DD + rg * 8;
      const f16x8 kf0 = *(const f16x8*)kr;
      const f16x8 kf1 = *(const f16x8*)(kr + 32);
      f32x4 z = {};
      z = __builtin_amdgcn_mfma_f32_16x16x32_f16(qf0, kf0, z, 0, 0, 0);
      const f32x4 sc = __builtin_amdgcn_mfma_f32_16x16x32_f16(qf1, kf1, z, 0, 0, 0);
#pragma unroll
      for (int j = 0; j < 4; ++j) {
        const float cj = (j == 0) ? Cm.x : (j == 1) ? Cm.y : (j == 2) ? Cm.z : Cm.w;
        const float p = exp2f(sc[j] - cj);
        acc[n][j] += ((mbits >> (j * 4 + n)) & 1u) ? p : 0.f;
      }
    }
  }
#pragma unroll
  for (int n = 0; n < 4; ++n)
#pragma unroll
    for (int j = 0; j < 4; ++j)
      outAvg[((size_t)b * SS + q0 + rg * 4 + j) * SS + k0 + n * 16 + cg] = acc[n][j] * 0.0625f;
}

// ---------------- launch ----------------
extern "C" void kernel_launch(void* const* d_in, const int* in_sizes, int n_in,
                              void* d_out, int out_size, void* d_ws, size_t ws_size,
                              hipStream_t stream) {
  const float* query = (const float*)d_in[0];
  const float* key_  = (const float*)d_in[1];
  const float* value = (const float*)d_in[2];
  const int*   mask  = (const int*)d_in[3];
  const float* Wq = (const float*)d_in[4];
  const float* bq = (const float*)d_in[5];
  const float* Wk = (const float*)d_in[6];
  const float* bk = (const float*)d_in[7];
  const float* Wv = (const float*)d_in[8];
  const float* bv = (const float*)d_in[9];
  const float* Wo = (const float*)d_in[10];
  const float* bo = (const float*)d_in[11];

  const size_t SZ_SE = (size_t)BB * SS * EE;  // 4,194,304
  h16* qx  = (h16*)d_ws;
  h16* kx  = qx + SZ_SE;
  h16* vx  = kx + SZ_SE;
  h16* wqx = vx + SZ_SE;
  h16* wkx = wqx + EE * EE;
  h16* wvx = wkx + EE * EE;
  h16* wox = wvx + EE * EE;
  h16* Qd  = wox + EE * EE;     // [B,H,S,D], pre-scaled by C1
  h16* Kd  = Qd + SZ_SE;        // [B,H,S,D]
  h16* Vtd = Kd + SZ_SE;        // [B,H,D,S]
  h16* Od  = Vtd + SZ_SE;       // [B,S,E]
  float* Cr = (float*)(Od + SZ_SE);                 // B*H*S floats
  unsigned long long* mpk = (unsigned long long*)(Cr + (size_t)BB * HH * SS);  // 1 MB

  float* outp = (float*)d_out;
  float* avgp = outp + SZ_SE;

  pack_mask<<<(BB * SS * SS) / 256, 256, 0, stream>>>(mask, mpk);
  cvt_qkv<<<dim3(4096, 3), 256, 0, stream>>>(query, key_, value, qx, kx, vx, (int)(SZ_SE / 4));
  cvt_w4<<<dim3(1024, 4), 256, 0, stream>>>(Wq, Wk, Wv, Wo, wqx, wkx, wvx, wox, EE * EE / 4);

  gemm_bt<0, true ><<<dim3(16, 64), 256, 0, stream>>>(qx, wqx, bq, Qd);
  gemm_bt<0, false><<<dim3(16, 64), 256, 0, stream>>>(kx, wkx, bk, Kd);
  gemm_bt<1, false><<<dim3(16, 64), 256, 0, stream>>>(vx, wvx, bv, Vtd);

  attn_fwd<<<dim3(SS / 128, BB * HH), 512, 0, stream>>>(Qd, Kd, Vtd, (const uint2*)mpk, Od, Cr);

  avg_attn_k<<<dim3(SS / 64, SS / 64, BB), 256, 0, stream>>>(Qd, Kd, (const uint2*)mpk, Cr, avgp);

  gemm_bt<2, false><<<dim3(16, 64), 256, 0, stream>>>(Od, wox, bo, outp);
}